// Round 1
// baseline (299.105 us; speedup 1.0000x reference)
//
#include <hip/hip_runtime.h>

// out[b,n] = sum_{c,hw} x[b,c,hw] * W_s[n,hw] * W_d[n,c] + W_b[n]
// B=512, C=384, N=512, HW=169 (13x13).
//
// R9: occupancy + merged epilogue.
//  - CT 128 -> 96 (4 c_blks/b, grid 2048). Xs = 96*200*2 = 38.4 KB -> 4 blocks/CU
//    (occupancy 33% -> 50%), __launch_bounds__(256,4) caps regs at 128.
//  - Waves: 2x2 quadrants of 48c x 64n (acc[3][4]); A-frag still feeds 4 ni.
//  - Single merged epilogue: s[nb][ni] (16 floats, fully unrolled = static
//    indexing, no scratch) accumulated across all 4 n-tiles; ONE shfl-reduce,
//    ONE red phase (aliased into Xs head, no extra LDS), 2 atomicAdd/thread.
//    Barriers/block: 9 -> 3. Compute phase = 288 unobstructed MFMA per wave.
//  - x read exactly once grid-wide (133 MB HBM floor); wsf/wdf/prep unchanged.

#define B_   512
#define C_   384
#define N_   512
#define HW_  169
#define CT_F 96      // fused-kernel c-tile rows
#define SXR  200     // Xs row stride in bf16 (16B-aligned rows, 2-way-free banks)

#define WSF_ELEMS  ((size_t)32 * 6 * 64 * 8)       // 98,304 bf16
#define WDF_ELEMS  ((size_t)24 * 32 * 64 * 4)      // 196,608 f32

typedef __bf16 bf16x8 __attribute__((ext_vector_type(8)));
typedef float f32x4  __attribute__((ext_vector_type(4)));
typedef float f32x4u __attribute__((ext_vector_type(4), aligned(4)));

__device__ __forceinline__ __bf16 f2bf(float f) {
  union { float f; unsigned u; } v; v.f = f;
  unsigned r = (v.u + 0x7FFFu + ((v.u >> 16) & 1u)) >> 16;   // RNE
  unsigned short s = (unsigned short)r;
  return __builtin_bit_cast(__bf16, s);
}

// hi16(a)|hi16(b)<<16 : two bf16 truncations in one v_perm
__device__ __forceinline__ unsigned pack_trunc(float a, float b) {
  return __builtin_amdgcn_perm(__builtin_bit_cast(unsigned, b),
                               __builtin_bit_cast(unsigned, a), 0x07060302u);
}

// ---------------- prep_aux: wsf (B-frag order) + wdf (C-layout order) ----------------
__global__ __launch_bounds__(256)
void prep_aux_kernel(const float* __restrict__ Ws,
                     const float* __restrict__ Wd,
                     __bf16* __restrict__ wsf,
                     float* __restrict__ wdf) {
  int t = blockIdx.x * 256 + threadIdx.x;      // 61440 total, exact
  if (t < 12288) {
    // wsf: t = (nm*6 + kb)*64 + lane ; lane(q=l>>4,m=l&15) holds Ws[nm*16+m][kb*32+q*8+j]
    int lane = t & 63;
    int fr   = t >> 6;
    int kb   = fr % 6;
    int nm   = fr / 6;
    int n    = nm * 16 + (lane & 15);
    int k0   = kb * 32 + (lane >> 4) * 8;
    const float* src = Ws + (size_t)n * HW_;
    bf16x8 v;
    #pragma unroll
    for (int j = 0; j < 8; ++j) {
      int k = k0 + j;
      float f = (k < HW_) ? src[k] : 0.f;
      v[j] = f2bf(f);
    }
    *(bf16x8*)(wsf + (size_t)t * 8) = v;
  } else {
    // wdf: t2 = (cm*32 + nm)*64 + lane; elem i = Wd[nm*16+(l&15)][cm*16+(l>>4)*4+i]
    int t2 = t - 12288;
    int lane = t2 & 63;
    int fr   = t2 >> 6;
    int nm   = fr & 31;
    int cm   = fr >> 5;
    int n    = nm * 16 + (lane & 15);
    int c0   = cm * 16 + (lane >> 4) * 4;
    f32x4 w = *(const f32x4u*)(Wd + (size_t)n * C_ + c0);
    *(f32x4*)(wdf + (size_t)t2 * 4) = w;
  }
}

// ---------------- fused main kernel ----------------
__global__ __launch_bounds__(256, 4)
void conv_fused(const float* __restrict__ x,
                const __bf16* __restrict__ wsf,
                const float* __restrict__ wdf,
                const float* __restrict__ Wb,
                float* __restrict__ out) {
  __shared__ __align__(16) __bf16 Xs[CT_F * SXR];   // 38.4 KB; head aliased as red[] post-compute

  const int tid  = threadIdx.x;
  // XCD swizzle: the 4 c_blks of one b land on the same id%8 slot (same XCD ->
  // out[b] atomics stay in one L2).
  const int id    = blockIdx.x;     // 0..2047
  const int slot  = id & 7;
  const int t8    = id >> 3;        // 0..255
  const int c_blk = t8 & 3;
  const int b     = (t8 >> 2) * 8 + slot;

  const int lane  = tid & 63;
  const int wv    = tid >> 6;          // 4 waves: 2x2 (c,n) 48x64 quadrants
  const int cq    = (wv >> 1) * 48;
  const int nq4   = (wv & 1) * 4;      // n-fragment offset within n-tile
  const int lrow  = lane & 15;
  const int lquad = lane >> 4;

  // ---- stage X tile: 96 rows x 169 cols fp32 -> bf16 (cols padded to 192) ----
  const float* src = x + ((size_t)b * C_ + (size_t)c_blk * CT_F) * HW_;
  // 96 rows x 48 chunks(4 cols) = 4608 items = 18/thread exact
  #pragma unroll 6
  for (int p = 0; p < 18; ++p) {
    int i   = p * 256 + tid;
    int row = i / 48;
    int ch  = i - row * 48;
    const float* bp = src + row * HW_ + ch * 4;
    float v0 = 0.f, v1 = 0.f, v2 = 0.f, v3 = 0.f;
    if (ch < 42) {                      // cols ch*4..+3 <= 167
      f32x4u t = *(const f32x4u*)bp;
      v0 = t[0]; v1 = t[1]; v2 = t[2]; v3 = t[3];
    } else if (ch == 42) {              // only col 168 valid
      v0 = bp[0];
    }                                    // ch 43..47: zero pad to col 191
    unsigned d0 = pack_trunc(v0, v1);
    unsigned d1 = pack_trunc(v2, v3);
    uint2 d; d.x = d0; d.y = d1;
    *(uint2*)&Xs[row * SXR + ch * 4] = d;
  }
  __syncthreads();   // lgkm drain only (no DMA queue)

  const int cm0 = c_blk * 6 + (cq >> 4);      // global 16-c fragment row (0..23)

  float s[4][4];     // [nb][ni] — all indexing static (loops fully unrolled)
  #pragma unroll
  for (int nb = 0; nb < 4; ++nb)
    #pragma unroll
    for (int ni = 0; ni < 4; ++ni)
      s[nb][ni] = 0.f;

  // ---- 4 n-tiles, X reused from LDS, NO barriers inside ----
  #pragma unroll
  for (int nb = 0; nb < 4; ++nb) {
    const int nm0 = nb * 8 + nq4;             // global 16-n fragment row (0..31)
    const __bf16* bbase = wsf + ((size_t)nm0 * 6) * 512 + (size_t)lane * 8;

    const f32x4 zero = {0.f, 0.f, 0.f, 0.f};
    f32x4 acc[3][4];
    #pragma unroll
    for (int mi = 0; mi < 3; ++mi)
      #pragma unroll
      for (int ni = 0; ni < 4; ++ni)
        acc[mi][ni] = zero;

    #pragma unroll
    for (int kb = 0; kb < 6; ++kb) {
      bf16x8 afr[3], bfr[4];
      #pragma unroll
      for (int mi = 0; mi < 3; ++mi)
        afr[mi] = *(const bf16x8*)&Xs[(cq + mi * 16 + lrow) * SXR + kb * 32 + lquad * 8];
      #pragma unroll
      for (int ni = 0; ni < 4; ++ni)
        bfr[ni] = *(const bf16x8*)(bbase + ((size_t)ni * 6 + kb) * 512);
      #pragma unroll
      for (int mi = 0; mi < 3; ++mi)
        #pragma unroll
        for (int ni = 0; ni < 4; ++ni)
          acc[mi][ni] = __builtin_amdgcn_mfma_f32_16x16x32_bf16(
              afr[mi], bfr[ni], acc[mi][ni], 0, 0, 0);
    }

    // fold acc * W_d into register-held s (wdf in C-layout order; R7-proven)
    const float* wbase = wdf + ((size_t)cm0 * 32 + nm0) * 256 + (size_t)lane * 4;
    #pragma unroll
    for (int ni = 0; ni < 4; ++ni) {
      float t = 0.f;
      #pragma unroll
      for (int mi = 0; mi < 3; ++mi) {
        const f32x4 w = *(const f32x4*)(wbase + ((size_t)mi * 32 + ni) * 256);
        t += acc[mi][ni][0] * w[0] + acc[mi][ni][1] * w[1]
           + acc[mi][ni][2] * w[2] + acc[mi][ni][3] * w[3];
      }
      s[nb][ni] = t;
    }
  }

  // ---- single merged epilogue ----
  // intra-wave quad combine (disjoint c within wave, same n)
  #pragma unroll
  for (int nb = 0; nb < 4; ++nb)
    #pragma unroll
    for (int ni = 0; ni < 4; ++ni) {
      s[nb][ni] += __shfl_xor(s[nb][ni], 16, 64);
      s[nb][ni] += __shfl_xor(s[nb][ni], 32, 64);
    }

  __syncthreads();   // all waves done reading Xs -> safe to alias as red
  float* red = reinterpret_cast<float*>(Xs);   // red[wv][256]: 4 KB of 38.4 KB
  if (lane < 16) {
    #pragma unroll
    for (int nb = 0; nb < 4; ++nb)
      #pragma unroll
      for (int ni = 0; ni < 4; ++ni)
        red[wv * 256 + nb * 64 + ni * 16 + lrow] = s[nb][ni];
  }
  __syncthreads();

  // waves {0,2} share n-half 0, {1,3} share n-half 1 (disjoint c halves)
  #pragma unroll
  for (int r = 0; r < 2; ++r) {
    const int n   = r * 256 + tid;
    const int nb  = n >> 7;
    const int rem = n & 127;
    const int h   = rem >> 6;          // which n-half -> wave pair {h, h+2}
    const int idx = rem & 63;
    float v = red[h * 256 + nb * 64 + idx] + red[(h + 2) * 256 + nb * 64 + idx];
    if (c_blk == 0) v += Wb[n];
    atomicAdd(&out[(size_t)b * N_ + n], v);
  }
}

// ---------------- fallback main kernel (no workspace needed) ----------------

#define CT   128
#define LDSS 104
#define KCH  96
#define NT   128

__global__ __launch_bounds__(256)
void conv_main_fallback(const float* __restrict__ x,
                        const float* __restrict__ Ws_g,
                        const float* __restrict__ Wd,
                        const float* __restrict__ Wb,
                        float* __restrict__ out) {
  __shared__ __align__(16) __bf16 Xs[CT][LDSS];
  __shared__ __align__(16) __bf16 Ws[NT][LDSS];

  const int tid   = threadIdx.x;
  const int n_blk = blockIdx.x;
  const int c_blk = blockIdx.y;
  const int b     = blockIdx.z;
  const int c0 = c_blk * CT;
  const int n0 = n_blk * NT;
  const int lane  = tid & 63;
  const int wv    = tid >> 6;
  const int cq    = (wv >> 1) * 64;
  const int nq    = (wv & 1) * 64;
  const int lrow  = lane & 15;
  const int lquad = lane >> 4;

  const f32x4 zero = {0.f, 0.f, 0.f, 0.f};
  f32x4 acc[4][4];
  #pragma unroll
  for (int mi = 0; mi < 4; ++mi)
    #pragma unroll
    for (int ni = 0; ni < 4; ++ni)
      acc[mi][ni] = zero;

  const float* xb  = x    + (size_t)b  * (C_ * HW_) + (size_t)c0 * HW_;
  const float* wsb = Ws_g + (size_t)n0 * HW_;

  for (int ch = 0; ch < 2; ++ch) {
    const int k0 = ch * KCH;
    __syncthreads();
    for (int e = tid; e < CT * KCH; e += 256) {
      int r   = e / KCH;
      int col = e - r * KCH;
      int k   = k0 + col;
      float vx = 0.f, vw = 0.f;
      if (k < HW_) {
        vx = xb [r * HW_ + k];
        vw = wsb[r * HW_ + k];
      }
      Xs[r][col] = f2bf(vx);
      Ws[r][col] = f2bf(vw);
    }
    __syncthreads();

    #pragma unroll
    for (int ks = 0; ks < 3; ++ks) {
      const int kc = ks * 32 + lquad * 8;
      bf16x8 afr[4], bfr[4];
      #pragma unroll
      for (int mi = 0; mi < 4; ++mi)
        afr[mi] = *(const bf16x8*)&Xs[cq + mi * 16 + lrow][kc];
      #pragma unroll
      for (int ni = 0; ni < 4; ++ni)
        bfr[ni] = *(const bf16x8*)&Ws[nq + ni * 16 + lrow][kc];
      #pragma unroll
      for (int mi = 0; mi < 4; ++mi)
        #pragma unroll
        for (int ni = 0; ni < 4; ++ni)
          acc[mi][ni] = __builtin_amdgcn_mfma_f32_16x16x32_bf16(
              afr[mi], bfr[ni], acc[mi][ni], 0, 0, 0);
    }
  }

  #pragma unroll
  for (int ni = 0; ni < 4; ++ni) {
    const int n = n0 + nq + ni * 16 + lrow;
    float sv = 0.f;
    #pragma unroll
    for (int mi = 0; mi < 4; ++mi) {
      const int cbase = c0 + cq + mi * 16 + lquad * 4;
      #pragma unroll
      for (int i = 0; i < 4; ++i)
        sv += acc[mi][ni][i] * Wd[(size_t)n * C_ + (cbase + i)];
    }
    sv += __shfl_xor(sv, 16, 64);
    sv += __shfl_xor(sv, 32, 64);
    if (lane < 16) {
      if (c_blk == 0 && cq == 0) sv += Wb[n];
      atomicAdd(&out[(size_t)b * N_ + n], sv);
    }
  }
}

extern "C" void kernel_launch(void* const* d_in, const int* in_sizes, int n_in,
                              void* d_out, int out_size, void* d_ws, size_t ws_size,
                              hipStream_t stream) {
  const float* x   = (const float*)d_in[0];   // [512,384,13,13]
  const float* Wsp = (const float*)d_in[1];   // [512,13,13]
  const float* Wd  = (const float*)d_in[2];   // [512,384]
  const float* Wb  = (const float*)d_in[3];   // [1,512]
  float* out = (float*)d_out;                 // [512,512] fp32

  hipMemsetAsync(d_out, 0, (size_t)out_size * sizeof(float), stream);

  const size_t need = WSF_ELEMS * sizeof(__bf16) + WDF_ELEMS * sizeof(float);

  if (ws_size >= need) {
    __bf16* wsf = (__bf16*)d_ws;
    float*  wdf = (float*)(wsf + WSF_ELEMS);

    prep_aux_kernel<<<240, 256, 0, stream>>>(Wsp, Wd, wsf, wdf);
    conv_fused<<<2048, 256, 0, stream>>>(x, wsf, wdf, Wb, out);
  } else {
    dim3 grid(N_ / NT, C_ / CT, B_);
    conv_main_fallback<<<grid, 256, 0, stream>>>(x, Wsp, Wd, Wb, out);
  }
}